// Round 7
// baseline (853.961 us; speedup 1.0000x reference)
//
#include <hip/hip_runtime.h>

#define TT   1024
#define NW   34          // 32-iter windows (lane 63 reaches iter 1086)
#define FINF 1e30f

// dirs layout (identical bit format to rounds 5/6, keyed by 64-row band):
//   uint2 {ne2_mask, diag_mask} at index ((b*16+bi)*NW + T)*64 + rr
//   where rr = row within band; stored bit k of window T = col 32T - o + k,
//   o = skew-lane that computed the row: o = (bi&3)*16 + (rr>>2).
// ne2 bit: dir != left. diag bit: dir == diag (first-min argmin).

// Pure-VALU lane shift: DPP row_shr:1 within 16-lane rows (supported on CDNA;
// it's the *wave*-level DPP modes that gfx90a+ removed — round-3 lesson).
// Lanes 0/16/32/48 keep 'old' (own value); caller patches them.
__device__ __forceinline__ float dpp_row_shr1(float v) {
    int r = __builtin_amdgcn_update_dpp(
        __float_as_int(v), __float_as_int(v), 0x111, 0xF, 0xF, false);
    return __int_as_float(r);
}
__device__ __forceinline__ float rdlane(float v, int l) {
    return __int_as_float(__builtin_amdgcn_readlane(__float_as_int(v), l));
}

// ---------------- K1: forward DP, 1 block (4 waves) per batch ----------------
// Wave w owns rows 256w..256w+255; lane L owns 4 rows 4L..4L+3 of that range.
// Continuous skew: at iter s, lane L computes col s-L for its 4 rows. The
// serial chain is DPP+readlane exchange + 4 dependent cells — NO LDS on chain.
// Wave-to-wave boundary rows via LDS mailboxes with sign-bit validity
// (costs >= 0; -1.0f init / 0xAA poison are negative), validated JIT per
// 8-col group. cur starts FINF for ALL lanes; (0,0) handled by the best>9e29
// clamp (round-2 proven; any other init leaks through the exchange chain).
__global__ __launch_bounds__(256) void dtw_forward(
    const float* __restrict__ preds,
    const float* __restrict__ targs,
    uint2* __restrict__ dirs)
{
    __shared__ float2 qsh[TT];
    __shared__ float mbox[3][TT];

    const int tid  = threadIdx.x;
    const int w    = tid >> 6;
    const int lane = tid & 63;
    const int b    = blockIdx.x;

    for (int k = tid; k < TT; k += 256) {
        float4 t4 = ((const float4*)targs)[(size_t)b * TT + k];
        qsh[k] = make_float2(t4.x, t4.y);
    }
    for (int k = tid; k < 3 * TT; k += 256) ((float*)mbox)[k] = -1.0f;

    float px[4], py[4];
#pragma unroll
    for (int k = 0; k < 4; ++k) {
        const int row = w * 256 + lane * 4 + k;
        float4 pv = ((const float4*)preds)[(size_t)b * TT + row];
        px[k] = pv.x; py[k] = pv.y;
    }
    __syncthreads();

    const float* src = (w > 0) ? mbox[w - 1] : nullptr;
    float*       dst = (w < 3) ? mbox[w]     : nullptr;

    float cur0 = FINF, cur1 = FINF, cur2 = FINF, cur3 = FINF;
    float uprev0 = FINF;
    unsigned au[4] = {0,0,0,0}, ad[4] = {0,0,0,0};
    float bnd[8];
#pragma unroll
    for (int k = 0; k < 8; ++k) bnd[k] = FINF;

    const int bb = b * 16 + 4 * w + (lane >> 4);   // 64-row band index
    const int r0 = (lane & 15) * 4;                // row within band
    const bool is63   = (lane == 63);
    const bool isHead = ((lane & 15) == 0);        // lanes 0,16,32,48

    for (int T = 0; T < NW; ++T) {
#pragma unroll 1
        for (int sub = 0; sub < 4; ++sub) {
            const int s0 = T * 32 + sub * 8;
            // off-chain: prefetch q pairs for this 8-group into registers
            float2 qv[8];
#pragma unroll
            for (int k2 = 0; k2 < 8; ++k2)
                qv[k2] = qsh[(s0 + k2 - lane) & (TT - 1)];
            if (w > 0 && s0 < TT) {
                // JIT validate boundary cols [s0, s0+7] (sign-bit test)
                for (;;) {
                    unsigned sg = 0u;
#pragma unroll
                    for (int k2 = 0; k2 < 8; ++k2) {
                        bnd[k2] = __hip_atomic_load(src + s0 + k2, __ATOMIC_RELAXED,
                                                    __HIP_MEMORY_SCOPE_WORKGROUP);
                        sg |= __float_as_uint(bnd[k2]);
                    }
                    if (!(sg & 0x80000000u)) break;
                    __builtin_amdgcn_s_sleep(1);
                }
            }
#pragma unroll
            for (int k2 = 0; k2 < 8; ++k2) {
                const int s = s0 + k2;
                float2 q = qv[k2];
                float dx0 = px[0] - q.x, dy0 = py[0] - q.y;
                float dx1 = px[1] - q.x, dy1 = py[1] - q.y;
                float dx2 = px[2] - q.x, dy2 = py[2] - q.y;
                float dx3 = px[3] - q.x, dy3 = py[3] - q.y;
                float d0 = sqrtf(dx0 * dx0 + dy0 * dy0);
                float d1 = sqrtf(dx1 * dx1 + dy1 * dy1);
                float d2 = sqrtf(dx2 * dx2 + dy2 * dy2);
                float d3 = sqrtf(dx3 * dx3 + dy3 * dy3);

                // pure-VALU exchange: lane L gets lane L-1's cur3 (post step s-1)
                float r15 = rdlane(cur3, 15);
                float r31 = rdlane(cur3, 31);
                float r47 = rdlane(cur3, 47);
                float sh  = dpp_row_shr1(cur3);
                float patch = (lane == 16) ? r15 : (lane == 32) ? r31 : r47;
                float u0 = isHead
                    ? ((lane == 0) ? ((w == 0) ? FINF : bnd[k2]) : patch)
                    : sh;

                const bool act = (lane <= s);
                float c0o = cur0, c1o = cur1, c2o = cur2, c3o = cur3;

                // row k=0: cd=uprev0, cu=u0, cl=c0o (clamp fires only at (0,0))
                float m2a = fminf(u0, c0o);
                float ba  = fminf(uprev0, m2a);
                ba = (ba > 9e29f) ? 0.0f : ba;
                float v0 = d0 + ba;
                unsigned bd0 = (uprev0 <= m2a) ? 1u : 0u;
                unsigned bu0 = ((u0 <= c0o) ? 1u : 0u) | bd0;
                // row k=1: cd=c0o, cu=v0, cl=c1o
                float m2b = fminf(v0, c1o);
                float v1 = d1 + fminf(c0o, m2b);
                unsigned bd1 = (c0o <= m2b) ? 1u : 0u;
                unsigned bu1 = ((v0 <= c1o) ? 1u : 0u) | bd1;
                // row k=2
                float m2c = fminf(v1, c2o);
                float v2 = d2 + fminf(c1o, m2c);
                unsigned bd2 = (c1o <= m2c) ? 1u : 0u;
                unsigned bu2 = ((v1 <= c2o) ? 1u : 0u) | bd2;
                // row k=3
                float m2d = fminf(v2, c3o);
                float v3 = d3 + fminf(c2o, m2d);
                unsigned bd3 = (c2o <= m2d) ? 1u : 0u;
                unsigned bu3 = ((v2 <= c3o) ? 1u : 0u) | bd3;

                au[0] = (au[0] << 1) | bu0;  ad[0] = (ad[0] << 1) | bd0;
                au[1] = (au[1] << 1) | bu1;  ad[1] = (ad[1] << 1) | bd1;
                au[2] = (au[2] << 1) | bu2;  ad[2] = (ad[2] << 1) | bd2;
                au[3] = (au[3] << 1) | bu3;  ad[3] = (ad[3] << 1) | bd3;

                cur0 = act ? v0 : c0o;
                cur1 = act ? v1 : c1o;
                cur2 = act ? v2 : c2o;
                cur3 = act ? v3 : c3o;
                uprev0 = u0;

                if (is63 && w < 3 && (unsigned)(s - 63) < 1024u)
                    __hip_atomic_store(dst + (s - 63), cur3, __ATOMIC_RELAXED,
                                       __HIP_MEMORY_SCOPE_WORKGROUP);
            }
        }
#pragma unroll
        for (int k = 0; k < 4; ++k) {
            dirs[(size_t)(bb * NW + T) * 64 + r0 + k] =
                make_uint2(__builtin_bitreverse32(au[k]), __builtin_bitreverse32(ad[k]));
            au[k] = 0u; ad[k] = 0u;
        }
    }
}

// ---------------- K2: parallel per-band walk (unchanged from r6) ----------------
__global__ __launch_bounds__(1024) void dtw_bandwalk(
    const float* __restrict__ preds,
    const float* __restrict__ targs,
    const float* __restrict__ subcoef,
    const uint2* __restrict__ dirs,
    float* __restrict__ seg,
    unsigned short* __restrict__ exitc)
{
    __shared__ uint2 raw[NW * 64];
    __shared__ unsigned nebit[64][32];
    __shared__ unsigned dgbit[64][32];
    __shared__ float2 qsh[TT];
    __shared__ float2 psh[64];

    const int tid = threadIdx.x;
    const int b   = blockIdx.x >> 4;
    const int bi  = blockIdx.x & 15;

    for (int i = tid; i < NW * 64; i += 1024)
        raw[i] = dirs[(size_t)(b * 16 + bi) * (NW * 64) + i];
    {
        float4 t4 = ((const float4*)targs)[(size_t)b * TT + tid];
        qsh[tid] = make_float2(t4.x, t4.y);
    }
    if (tid < 64) {
        float4 p4 = ((const float4*)preds)[(size_t)b * TT + bi * 64 + tid];
        psh[tid] = make_float2(p4.x, p4.y);
    }
    __syncthreads();

    // realign skewed windows to row-major 32-col dwords
    for (int i = tid; i < 64 * 32; i += 1024) {
        const int rr = i >> 5, u = i & 31;
        const int o  = ((bi & 3) << 4) + (rr >> 2);
        const int T0 = u + (o >> 5);
        const int sh = o & 31;
        uint2 A = raw[T0 * 64 + rr];
        uint2 Bv = raw[(T0 + 1) * 64 + rr];
        nebit[rr][u] = sh ? ((A.x >> sh) | (Bv.x << (32 - sh))) : A.x;
        dgbit[rr][u] = sh ? ((A.y >> sh) | (Bv.y << (32 - sh))) : A.y;
    }
    __syncthreads();

    const float sc0 = subcoef[0], sc1 = subcoef[1];
    int j = tid;            // entry column
    float loss = 0.0f;

    for (int rr = 63; rr >= 0; --rr) {
        float2 p = psh[rr];
        for (;;) {
            const int u = j >> 5, m = j & 31;
            unsigned wne = nebit[rr][u] << (31 - m);   // bit31 = col j
            if (wne == 0u) {
                for (int c = j; c >= (u << 5); --c) {
                    float2 q = qsh[c];
                    loss += fabsf(p.x - q.x) * sc0 + fabsf(p.y - q.y) * sc1;
                }
                j = (u << 5) - 1;    // col-0 ne bit is always 1 -> u>0 here
                continue;
            }
            const int cz = __builtin_clz(wne);
            const int j2 = j - cz;
            for (int c = j; c >= j2; --c) {
                float2 q = qsh[c];
                loss += fabsf(p.x - q.x) * sc0 + fabsf(p.y - q.y) * sc1;
            }
            if (rr > 0 || bi > 0) {
                const int diag = (int)((dgbit[rr][j2 >> 5] >> (j2 & 31)) & 1u);
                j = j2 - diag;
            } else {
                j = 0;
            }
            break;
        }
    }
    const size_t oidx = ((size_t)(b * 16 + bi) << 10) + tid;
    seg[oidx] = loss;
    exitc[oidx] = (unsigned short)j;
}

// ---------------- K3: stitch ----------------
__global__ void dtw_stitch(const float* __restrict__ seg,
                           const unsigned short* __restrict__ exitc,
                           float* __restrict__ out)
{
    const int b = threadIdx.x;
    float loss = 0.0f;
    int j = TT - 1;
    for (int bi = 15; bi >= 0; --bi) {
        const size_t idx = ((size_t)(b * 16 + bi) << 10) + j;
        loss += seg[idx];
        j = exitc[idx];
    }
    atomicAdd(out, loss);
}

extern "C" void kernel_launch(void* const* d_in, const int* in_sizes, int n_in,
                              void* d_out, int out_size, void* d_ws, size_t ws_size,
                              hipStream_t stream)
{
    const float* preds   = (const float*)d_in[0];
    const float* targs   = (const float*)d_in[1];
    const float* subcoef = (const float*)d_in[2];
    float* out = (float*)d_out;

    const int B = in_sizes[0] / (TT * 4);

    const size_t dirsBytes = (size_t)B * 16 * NW * 64 * sizeof(uint2);   // ~17.8 MB @ B=64
    const size_t segBytes  = (size_t)B * 16 * 1024 * sizeof(float);      // 4 MB
    uint2* dirs = (uint2*)d_ws;
    float* seg  = (float*)((char*)d_ws + dirsBytes);
    unsigned short* exitc = (unsigned short*)((char*)d_ws + dirsBytes + segBytes);

    hipMemsetAsync(out, 0, sizeof(float), stream);
    dtw_forward<<<dim3(B), dim3(256), 0, stream>>>(preds, targs, dirs);
    dtw_bandwalk<<<dim3(B * 16), dim3(1024), 0, stream>>>(preds, targs, subcoef, dirs, seg, exitc);
    dtw_stitch<<<dim3(1), dim3(B), 0, stream>>>(seg, exitc, out);
}

// Round 8
// 727.903 us; speedup vs baseline: 1.1732x; 1.1732x over previous
//
#include <hip/hip_runtime.h>

#define TT   1024
#define NW   34          // 32-iter windows (lane 63 reaches iter 1086)
#define FINF 1e30f

// dirs layout (identical bit format to rounds 5-7, keyed by 64-row band):
//   uint2 {ne2_mask, diag_mask} at index ((b*16+bi)*NW + T)*64 + rr
//   where rr = row within band; stored bit k of window T = col 32T - o + k,
//   o = skew-lane that computed the row: o = (bi&3)*16 + (rr>>2).
// ne2 bit: dir != left. diag bit: dir == diag (first-min argmin).

// ---------------- K1: forward DP, 1 block (4 waves) per batch ----------------
// Wave w owns rows 256w..256w+255; lane L owns rows 4L..4L+3 of that range.
// Continuous skew: at iter s, lane L computes col s-L for its 4 rows.
// Exchange via __shfl_up (r6-proven; r7's readlane/DPP variant measured worse).
// q comes from GLOBAL in 8-col register batches (vmcnt, off the lgkm chain) —
// the only per-step LDS ops are the bpermute and lane-63's mailbox write.
// Wave-to-wave boundary rows via LDS mailboxes with sign-bit validity
// (costs >= 0; -1.0f init / 0xAA poison are negative), JIT-validated per
// 8-col group. cur starts FINF for ALL lanes; (0,0) handled by the best>9e29
// clamp (round-2 proven; any other init leaks through the exchange chain).
__global__ __launch_bounds__(256) void dtw_forward(
    const float* __restrict__ preds,
    const float* __restrict__ targs,
    uint2* __restrict__ dirs)
{
    __shared__ float mbox[3][TT];

    const int tid  = threadIdx.x;
    const int w    = tid >> 6;
    const int lane = tid & 63;
    const int b    = blockIdx.x;

    for (int k = tid; k < 3 * TT; k += 256) ((float*)mbox)[k] = -1.0f;

    float px[4], py[4];
#pragma unroll
    for (int k = 0; k < 4; ++k) {
        const int row = w * 256 + lane * 4 + k;
        float4 pv = ((const float4*)preds)[(size_t)b * TT + row];
        px[k] = pv.x; py[k] = pv.y;
    }
    __syncthreads();

    const float* src = (w > 0) ? mbox[w - 1] : nullptr;
    float*       dst = (w < 3) ? mbox[w]     : nullptr;
    const float* qb  = targs + (size_t)b * TT * 4;

    float cur0 = FINF, cur1 = FINF, cur2 = FINF, cur3 = FINF;
    float uprev0 = FINF;
    unsigned au[4] = {0,0,0,0}, ad[4] = {0,0,0,0};
    float bnd[8];
#pragma unroll
    for (int k = 0; k < 8; ++k) bnd[k] = FINF;

    const int bb = b * 16 + 4 * w + (lane >> 4);   // 64-row band index
    const int r0 = (lane & 15) * 4;                // row within band
    const bool is63 = (lane == 63);

    float shp = __shfl_up(cur3, 1);   // pipelined up-neighbor (FINF initially)

    for (int T = 0; T < NW; ++T) {
#pragma unroll 1
        for (int sub = 0; sub < 4; ++sub) {
            const int s0 = T * 32 + sub * 8;
            // q for this 8-group from GLOBAL into registers (vmcnt batch)
            float qx[8], qy[8];
#pragma unroll
            for (int k2 = 0; k2 < 8; ++k2) {
                const int c = (s0 + k2 - lane) & (TT - 1);
                float2 qv = *(const float2*)(qb + c * 4);
                qx[k2] = qv.x; qy[k2] = qv.y;
            }
            if (w > 0 && s0 < TT) {
                // JIT validate boundary cols [s0, s0+7] (sign-bit test, no sleep)
                for (;;) {
                    unsigned sg = 0u;
#pragma unroll
                    for (int k2 = 0; k2 < 8; ++k2) {
                        bnd[k2] = __hip_atomic_load(src + s0 + k2, __ATOMIC_RELAXED,
                                                    __HIP_MEMORY_SCOPE_WORKGROUP);
                        sg |= __float_as_uint(bnd[k2]);
                    }
                    if (!(sg & 0x80000000u)) break;
                }
            }
#pragma unroll
            for (int k2 = 0; k2 < 8; ++k2) {
                const int s = s0 + k2;
                float dx0 = px[0] - qx[k2], dy0 = py[0] - qy[k2];
                float dx1 = px[1] - qx[k2], dy1 = py[1] - qy[k2];
                float dx2 = px[2] - qx[k2], dy2 = py[2] - qy[k2];
                float dx3 = px[3] - qx[k2], dy3 = py[3] - qy[k2];
                float d0 = sqrtf(dx0 * dx0 + dy0 * dy0);
                float d1 = sqrtf(dx1 * dx1 + dy1 * dy1);
                float d2 = sqrtf(dx2 * dx2 + dy2 * dy2);
                float d3 = sqrtf(dx3 * dx3 + dy3 * dy3);

                float u0 = (lane == 0) ? ((w == 0) ? FINF : bnd[k2]) : shp;
                const bool act = (lane <= s);
                float c0o = cur0, c1o = cur1, c2o = cur2, c3o = cur3;

                // row k=0: cd=uprev0, cu=u0, cl=c0o (clamp fires only at (0,0))
                float m2a = fminf(u0, c0o);
                float ba  = fminf(uprev0, m2a);
                ba = (ba > 9e29f) ? 0.0f : ba;
                float v0 = d0 + ba;
                unsigned bd0 = (uprev0 <= m2a) ? 1u : 0u;
                unsigned bu0 = ((u0 <= c0o) ? 1u : 0u) | bd0;
                // row k=1: cd=c0o, cu=v0, cl=c1o
                float m2b = fminf(v0, c1o);
                float v1 = d1 + fminf(c0o, m2b);
                unsigned bd1 = (c0o <= m2b) ? 1u : 0u;
                unsigned bu1 = ((v0 <= c1o) ? 1u : 0u) | bd1;
                // row k=2
                float m2c = fminf(v1, c2o);
                float v2 = d2 + fminf(c1o, m2c);
                unsigned bd2 = (c1o <= m2c) ? 1u : 0u;
                unsigned bu2 = ((v1 <= c2o) ? 1u : 0u) | bd2;
                // row k=3
                float m2d = fminf(v2, c3o);
                float v3 = d3 + fminf(c2o, m2d);
                unsigned bd3 = (c2o <= m2d) ? 1u : 0u;
                unsigned bu3 = ((v2 <= c3o) ? 1u : 0u) | bd3;

                au[0] = (au[0] << 1) | bu0;  ad[0] = (ad[0] << 1) | bd0;
                au[1] = (au[1] << 1) | bu1;  ad[1] = (ad[1] << 1) | bd1;
                au[2] = (au[2] << 1) | bu2;  ad[2] = (ad[2] << 1) | bd2;
                au[3] = (au[3] << 1) | bu3;  ad[3] = (ad[3] << 1) | bd3;

                cur0 = act ? v0 : c0o;
                cur1 = act ? v1 : c1o;
                cur2 = act ? v2 : c2o;
                cur3 = act ? v3 : c3o;
                uprev0 = u0;

                if (is63 && w < 3 && (unsigned)(s - 63) < 1024u)
                    __hip_atomic_store(dst + (s - 63), cur3, __ATOMIC_RELAXED,
                                       __HIP_MEMORY_SCOPE_WORKGROUP);

                shp = __shfl_up(cur3, 1);   // for next iter (col s+1-L)
            }
        }
#pragma unroll
        for (int k = 0; k < 4; ++k) {
            dirs[(size_t)(bb * NW + T) * 64 + r0 + k] =
                make_uint2(__builtin_bitreverse32(au[k]), __builtin_bitreverse32(ad[k]));
            au[k] = 0u; ad[k] = 0u;
        }
    }
}

// ---------------- K2: row-synchronous per-band walk ----------------
// Block = (batch, band), 1024 threads = 1024 entry-column walkers. All
// walkers are at the same band-row simultaneously, so per row: block-wide
// cell-loss prefix sum F, then each walker does O(1) (+rare word skips) via
// loss += F[j+1]-F[jl]. No divergent per-column loss loops.
__global__ __launch_bounds__(1024) void dtw_bandwalk(
    const float* __restrict__ preds,
    const float* __restrict__ targs,
    const float* __restrict__ subcoef,
    const uint2* __restrict__ dirs,
    float* __restrict__ seg,
    unsigned short* __restrict__ exitc)
{
    __shared__ uint2 raw[NW * 64];
    __shared__ unsigned nebit[64][32];
    __shared__ unsigned dgbit[64][32];
    __shared__ float Fsh[TT + 1];
    __shared__ float2 psh[64];
    __shared__ float wsum[16];

    const int tid  = threadIdx.x;
    const int wid  = tid >> 6;
    const int lane = tid & 63;
    const int b    = blockIdx.x >> 4;
    const int bi   = blockIdx.x & 15;

    for (int i = tid; i < NW * 64; i += 1024)
        raw[i] = dirs[(size_t)(b * 16 + bi) * (NW * 64) + i];
    if (tid < 64) {
        float4 p4 = ((const float4*)preds)[(size_t)b * TT + bi * 64 + tid];
        psh[tid] = make_float2(p4.x, p4.y);
    }
    // own q (thread = fixed column)
    const float* tb = targs + ((size_t)b * TT + tid) * 4;
    const float qx = tb[0], qy = tb[1];
    const float sc0 = subcoef[0], sc1 = subcoef[1];
    __syncthreads();

    // realign skewed windows to row-major 32-col dwords
    for (int i = tid; i < 64 * 32; i += 1024) {
        const int rr = i >> 5, u = i & 31;
        const int o  = ((bi & 3) << 4) + (rr >> 2);
        const int T0 = u + (o >> 5);
        const int sh = o & 31;
        uint2 A  = raw[T0 * 64 + rr];
        uint2 Bv = raw[(T0 + 1) * 64 + rr];
        nebit[rr][u] = sh ? ((A.x >> sh) | (Bv.x << (32 - sh))) : A.x;
        dgbit[rr][u] = sh ? ((A.y >> sh) | (Bv.y << (32 - sh))) : A.y;
    }
    __syncthreads();

    int j = tid;          // walker state: current column
    float loss = 0.0f;

    for (int rr = 63; rr >= 0; --rr) {
        float2 p = psh[rr];
        float v = fabsf(p.x - qx) * sc0 + fabsf(p.y - qy) * sc1;
        // wave-inclusive scan
#pragma unroll
        for (int off = 1; off < 64; off <<= 1) {
            float tv = __shfl_up(v, off);
            v += (lane >= off) ? tv : 0.0f;
        }
        if (lane == 63) wsum[wid] = v;
        __syncthreads();   // also fences previous row's walker Fsh reads
        float base = 0.0f;
#pragma unroll
        for (int ww = 0; ww < 15; ++ww) {
            float t = wsum[ww];
            base += (ww < wid) ? t : 0.0f;
        }
        Fsh[tid + 1] = base + v;
        if (tid == 0) Fsh[0] = 0.0f;
        __syncthreads();

        // walker step (O(1) + rare word skips)
        if (bi == 0 && rr == 0) {
            loss += Fsh[j + 1] - Fsh[0];
            j = 0;
        } else {
            int u = j >> 5, m = j & 31;
            unsigned wv = nebit[rr][u] << (31 - m);
            while (wv == 0u) { --u; m = 31; wv = nebit[rr][u]; }
            const int cz = __builtin_clz(wv);
            const int j2 = (u << 5) + m - cz;
            loss += Fsh[j + 1] - Fsh[j2];
            const int diag = (int)((dgbit[rr][j2 >> 5] >> (j2 & 31)) & 1u);
            j = j2 - diag;
        }
    }

    const size_t oidx = ((size_t)(b * 16 + bi) << 10) + tid;
    seg[oidx] = loss;
    exitc[oidx] = (unsigned short)j;
}

// ---------------- K3: stitch ----------------
__global__ void dtw_stitch(const float* __restrict__ seg,
                           const unsigned short* __restrict__ exitc,
                           float* __restrict__ out)
{
    const int b = threadIdx.x;
    float loss = 0.0f;
    int j = TT - 1;
    for (int bi = 15; bi >= 0; --bi) {
        const size_t idx = ((size_t)(b * 16 + bi) << 10) + j;
        loss += seg[idx];
        j = exitc[idx];
    }
    atomicAdd(out, loss);
}

extern "C" void kernel_launch(void* const* d_in, const int* in_sizes, int n_in,
                              void* d_out, int out_size, void* d_ws, size_t ws_size,
                              hipStream_t stream)
{
    const float* preds   = (const float*)d_in[0];
    const float* targs   = (const float*)d_in[1];
    const float* subcoef = (const float*)d_in[2];
    float* out = (float*)d_out;

    const int B = in_sizes[0] / (TT * 4);

    const size_t dirsBytes = (size_t)B * 16 * NW * 64 * sizeof(uint2);   // ~17.8 MB @ B=64
    const size_t segBytes  = (size_t)B * 16 * 1024 * sizeof(float);      // 4 MB
    uint2* dirs = (uint2*)d_ws;
    float* seg  = (float*)((char*)d_ws + dirsBytes);
    unsigned short* exitc = (unsigned short*)((char*)d_ws + dirsBytes + segBytes);

    hipMemsetAsync(out, 0, sizeof(float), stream);
    dtw_forward<<<dim3(B), dim3(256), 0, stream>>>(preds, targs, dirs);
    dtw_bandwalk<<<dim3(B * 16), dim3(1024), 0, stream>>>(preds, targs, subcoef, dirs, seg, exitc);
    dtw_stitch<<<dim3(1), dim3(B), 0, stream>>>(seg, exitc, out);
}

// Round 9
// 667.429 us; speedup vs baseline: 1.2795x; 1.0906x over previous
//
#include <hip/hip_runtime.h>

#define TT   1024
#define NW   34          // 32-iter windows (lane 63 reaches iter 1086)
#define FINF 1e30f

template<bool A> struct BoolC { static constexpr bool value = A; };

// dirs layout (identical bit format to rounds 5-8, keyed by 64-row band):
//   uint2 {ne2_mask, diag_mask} at index ((b*16+bi)*NW + T)*64 + rr
//   where rr = row within band; stored bit k of window T = col 32T - o + k,
//   o = skew-lane that computed the row: o = (bi&3)*16 + (rr>>2).
// ne2 bit: dir != left. diag bit: dir == diag (first-min argmin).

// ---------------- K1: forward DP, 2 batches per block (8 waves) -------------
// Waves 0-3 -> batch A, waves 4-7 -> batch B (2 waves/SIMD: TLP hides the
// bpermute + dependency latency that pinned rounds 5-8 at ~490us).
// Within a batch: wave w owns rows 256w..+255; lane L owns rows 4L..4L+3.
// Continuous skew; exchange via __shfl_up (r6-proven). q from global in 8-col
// register batches (vmcnt, off the lgkm chain). Mailboxes sign-bit-valid.
// cur starts FINF for ALL lanes; (0,0) handled by the best>9e29 clamp, which
// lives only in the ACT prologue (T<2) — it can't fire for s>=64.
__global__ __launch_bounds__(512) void dtw_forward(
    const float* __restrict__ preds,
    const float* __restrict__ targs,
    uint2* __restrict__ dirs)
{
    __shared__ float mbox[2][3][TT];

    const int tid  = threadIdx.x;
    const int half = tid >> 8;
    const int w    = (tid >> 6) & 3;
    const int lane = tid & 63;
    const int b    = blockIdx.x * 2 + half;

    for (int k = tid; k < 2 * 3 * TT; k += 512) ((float*)mbox)[k] = -1.0f;

    float px[4], py[4];
#pragma unroll
    for (int k = 0; k < 4; ++k) {
        const int row = w * 256 + lane * 4 + k;
        float4 pv = ((const float4*)preds)[(size_t)b * TT + row];
        px[k] = pv.x; py[k] = pv.y;
    }
    __syncthreads();

    const float* src = (w > 0) ? mbox[half][w - 1] : nullptr;
    float*       dst = (w < 3) ? mbox[half][w]     : nullptr;
    const float* qb  = targs + (size_t)b * TT * 4;

    float cur0 = FINF, cur1 = FINF, cur2 = FINF, cur3 = FINF;
    float uprev0 = FINF;
    unsigned au[4] = {0,0,0,0}, ad[4] = {0,0,0,0};
    float bnd[8];
#pragma unroll
    for (int k = 0; k < 8; ++k) bnd[k] = FINF;

    const int bb = b * 16 + 4 * w + (lane >> 4);   // 64-row band index
    const int r0 = (lane & 15) * 4;                // row within band
    const bool is63 = (lane == 63);

    float shp = __shfl_up(cur3, 1);   // pipelined up-neighbor (FINF initially)

    for (int T = 0; T < NW; ++T) {
        auto sub4 = [&](auto actc) {
            constexpr bool ACT = decltype(actc)::value;
#pragma unroll 1
            for (int sub = 0; sub < 4; ++sub) {
                const int s0 = T * 32 + sub * 8;
                float qx[8], qy[8];
#pragma unroll
                for (int k2 = 0; k2 < 8; ++k2) {
                    const int c = (s0 + k2 - lane) & (TT - 1);
                    float2 qv = *(const float2*)(qb + c * 4);
                    qx[k2] = qv.x; qy[k2] = qv.y;
                }
                if (w > 0 && s0 < TT) {
                    for (;;) {   // JIT validate boundary cols (sign-bit test)
                        unsigned sg = 0u;
#pragma unroll
                        for (int k2 = 0; k2 < 8; ++k2) {
                            bnd[k2] = __hip_atomic_load(src + s0 + k2, __ATOMIC_RELAXED,
                                                        __HIP_MEMORY_SCOPE_WORKGROUP);
                            sg |= __float_as_uint(bnd[k2]);
                        }
                        if (!(sg & 0x80000000u)) break;
                    }
                }
#pragma unroll
                for (int k2 = 0; k2 < 8; ++k2) {
                    const int s = s0 + k2;
                    float dx0 = px[0] - qx[k2], dy0 = py[0] - qy[k2];
                    float dx1 = px[1] - qx[k2], dy1 = py[1] - qy[k2];
                    float dx2 = px[2] - qx[k2], dy2 = py[2] - qy[k2];
                    float dx3 = px[3] - qx[k2], dy3 = py[3] - qy[k2];
                    float d0 = __builtin_amdgcn_sqrtf(dx0 * dx0 + dy0 * dy0);
                    float d1 = __builtin_amdgcn_sqrtf(dx1 * dx1 + dy1 * dy1);
                    float d2 = __builtin_amdgcn_sqrtf(dx2 * dx2 + dy2 * dy2);
                    float d3 = __builtin_amdgcn_sqrtf(dx3 * dx3 + dy3 * dy3);

                    float u0 = (lane == 0) ? ((w == 0) ? FINF : bnd[k2]) : shp;
                    float c0o = cur0, c1o = cur1, c2o = cur2, c3o = cur3;

                    float m2a = fminf(u0, c0o);
                    float ba  = fminf(uprev0, m2a);
                    if constexpr (ACT) ba = (ba > 9e29f) ? 0.0f : ba;  // (0,0) only
                    float v0 = d0 + ba;
                    unsigned bd0 = (uprev0 <= m2a) ? 1u : 0u;
                    unsigned bu0 = ((u0 <= c0o) ? 1u : 0u) | bd0;
                    float m2b = fminf(v0, c1o);
                    float v1 = d1 + fminf(c0o, m2b);
                    unsigned bd1 = (c0o <= m2b) ? 1u : 0u;
                    unsigned bu1 = ((v0 <= c1o) ? 1u : 0u) | bd1;
                    float m2c = fminf(v1, c2o);
                    float v2 = d2 + fminf(c1o, m2c);
                    unsigned bd2 = (c1o <= m2c) ? 1u : 0u;
                    unsigned bu2 = ((v1 <= c2o) ? 1u : 0u) | bd2;
                    float m2d = fminf(v2, c3o);
                    float v3 = d3 + fminf(c2o, m2d);
                    unsigned bd3 = (c2o <= m2d) ? 1u : 0u;
                    unsigned bu3 = ((v2 <= c3o) ? 1u : 0u) | bd3;

                    au[0] = (au[0] << 1) | bu0;  ad[0] = (ad[0] << 1) | bd0;
                    au[1] = (au[1] << 1) | bu1;  ad[1] = (ad[1] << 1) | bd1;
                    au[2] = (au[2] << 1) | bu2;  ad[2] = (ad[2] << 1) | bd2;
                    au[3] = (au[3] << 1) | bu3;  ad[3] = (ad[3] << 1) | bd3;

                    if constexpr (ACT) {
                        const bool act = (lane <= s);
                        cur0 = act ? v0 : c0o;
                        cur1 = act ? v1 : c1o;
                        cur2 = act ? v2 : c2o;
                        cur3 = act ? v3 : c3o;
                    } else {
                        cur0 = v0; cur1 = v1; cur2 = v2; cur3 = v3;
                    }
                    uprev0 = u0;

                    if (is63 && w < 3 && (unsigned)(s - 63) < 1024u)
                        __hip_atomic_store(dst + (s - 63), cur3, __ATOMIC_RELAXED,
                                           __HIP_MEMORY_SCOPE_WORKGROUP);

                    shp = __shfl_up(cur3, 1);   // for next iter (col s+1-L)
                }
            }
        };
        if (T < 2) sub4(BoolC<true>{}); else sub4(BoolC<false>{});
#pragma unroll
        for (int k = 0; k < 4; ++k) {
            dirs[(size_t)(bb * NW + T) * 64 + r0 + k] =
                make_uint2(__builtin_bitreverse32(au[k]), __builtin_bitreverse32(ad[k]));
            au[k] = 0u; ad[k] = 0u;
        }
    }
}

// ---------------- K2: barrier-free per-band walk ----------------
// Block = (batch, band), 1024 walkers (one per entry column). Setup: realign
// masks (r8-proven), precompute per-row word sums + prefix Fw. Walk: per row,
// clz finds the left-run; loss = direct partial-word sums + Fw diffs for full
// words. No per-row barriers.
__global__ __launch_bounds__(1024) void dtw_bandwalk(
    const float* __restrict__ preds,
    const float* __restrict__ targs,
    const float* __restrict__ subcoef,
    const uint2* __restrict__ dirs,
    float* __restrict__ seg,
    unsigned short* __restrict__ exitc)
{
    __shared__ uint2 raw[NW * 64];
    __shared__ unsigned nebit[64][32];
    __shared__ unsigned dgbit[64][32];
    __shared__ float2 qsh[TT];
    __shared__ float2 psh[64];
    __shared__ float Fw[64][33];   // Fw[rr][u] = sum of D over words [0,u)

    const int tid = threadIdx.x;
    const int b   = blockIdx.x >> 4;
    const int bi  = blockIdx.x & 15;

    for (int i = tid; i < NW * 64; i += 1024)
        raw[i] = dirs[(size_t)(b * 16 + bi) * (NW * 64) + i];
    {
        float4 t4 = ((const float4*)targs)[(size_t)b * TT + tid];
        qsh[tid] = make_float2(t4.x, t4.y);
    }
    if (tid < 64) {
        float4 p4 = ((const float4*)preds)[(size_t)b * TT + bi * 64 + tid];
        psh[tid] = make_float2(p4.x, p4.y);
    }
    const float sc0 = subcoef[0], sc1 = subcoef[1];
    __syncthreads();

    // realign skewed windows to row-major 32-col dwords (r8-proven)
    for (int i = tid; i < 64 * 32; i += 1024) {
        const int rr = i >> 5, u = i & 31;
        const int o  = ((bi & 3) << 4) + (rr >> 2);
        const int T0 = u + (o >> 5);
        const int sh = o & 31;
        uint2 A  = raw[T0 * 64 + rr];
        uint2 Bv = raw[(T0 + 1) * 64 + rr];
        nebit[rr][u] = sh ? ((A.x >> sh) | (Bv.x << (32 - sh))) : A.x;
        dgbit[rr][u] = sh ? ((A.y >> sh) | (Bv.y << (32 - sh))) : A.y;
    }
    // per-row word sums of the loss field
    for (int i = tid; i < 64 * 32; i += 1024) {
        const int rr = i >> 5, u = i & 31;
        float2 p = psh[rr];
        float sum = 0.0f;
        for (int c = u * 32; c < u * 32 + 32; ++c) {
            float2 q = qsh[c];
            sum += fabsf(p.x - q.x) * sc0 + fabsf(p.y - q.y) * sc1;
        }
        Fw[rr][u + 1] = sum;
    }
    __syncthreads();
    if (tid < 64) {
        float acc = 0.0f;
        Fw[tid][0] = 0.0f;
        for (int u = 0; u < 32; ++u) { acc += Fw[tid][u + 1]; Fw[tid][u + 1] = acc; }
    }
    __syncthreads();

    int j = tid;          // walker: current column
    float loss = 0.0f;

    for (int rr = 63; rr >= 0; --rr) {
        float2 p = psh[rr];
        const bool origin = (bi == 0 && rr == 0);
        int j2;
        if (origin) j2 = 0;
        else {
            int u = j >> 5, m = j & 31;
            unsigned wv = nebit[rr][u] << (31 - m);
            while (wv == 0u) { --u; m = 31; wv = nebit[rr][u]; }
            const int cz = __builtin_clz(wv);
            j2 = (u << 5) + m - cz;
        }
        // loss over cols [j2 .. j] of row rr
        const int ua = j >> 5, ub = j2 >> 5;
        if (ua == ub) {
            for (int c = j2; c <= j; ++c) {
                float2 q = qsh[c];
                loss += fabsf(p.x - q.x) * sc0 + fabsf(p.y - q.y) * sc1;
            }
        } else {
            for (int c = (ua << 5); c <= j; ++c) {
                float2 q = qsh[c];
                loss += fabsf(p.x - q.x) * sc0 + fabsf(p.y - q.y) * sc1;
            }
            loss += Fw[rr][ua] - Fw[rr][ub + 1];
            for (int c = j2; c < (ub << 5) + 32; ++c) {
                float2 q = qsh[c];
                loss += fabsf(p.x - q.x) * sc0 + fabsf(p.y - q.y) * sc1;
            }
        }
        if (origin) j = 0;
        else {
            const int diag = (int)((dgbit[rr][j2 >> 5] >> (j2 & 31)) & 1u);
            j = j2 - diag;
        }
    }

    const size_t oidx = ((size_t)(b * 16 + bi) << 10) + tid;
    seg[oidx] = loss;
    exitc[oidx] = (unsigned short)j;
}

// ---------------- K3: stitch ----------------
__global__ void dtw_stitch(const float* __restrict__ seg,
                           const unsigned short* __restrict__ exitc,
                           float* __restrict__ out)
{
    const int b = threadIdx.x;
    float loss = 0.0f;
    int j = TT - 1;
    for (int bi = 15; bi >= 0; --bi) {
        const size_t idx = ((size_t)(b * 16 + bi) << 10) + j;
        loss += seg[idx];
        j = exitc[idx];
    }
    atomicAdd(out, loss);
}

extern "C" void kernel_launch(void* const* d_in, const int* in_sizes, int n_in,
                              void* d_out, int out_size, void* d_ws, size_t ws_size,
                              hipStream_t stream)
{
    const float* preds   = (const float*)d_in[0];
    const float* targs   = (const float*)d_in[1];
    const float* subcoef = (const float*)d_in[2];
    float* out = (float*)d_out;

    const int B = in_sizes[0] / (TT * 4);

    const size_t dirsBytes = (size_t)B * 16 * NW * 64 * sizeof(uint2);   // ~17.8 MB @ B=64
    const size_t segBytes  = (size_t)B * 16 * 1024 * sizeof(float);      // 4 MB
    uint2* dirs = (uint2*)d_ws;
    float* seg  = (float*)((char*)d_ws + dirsBytes);
    unsigned short* exitc = (unsigned short*)((char*)d_ws + dirsBytes + segBytes);

    hipMemsetAsync(out, 0, sizeof(float), stream);
    dtw_forward<<<dim3(B / 2), dim3(512), 0, stream>>>(preds, targs, dirs);
    dtw_bandwalk<<<dim3(B * 16), dim3(1024), 0, stream>>>(preds, targs, subcoef, dirs, seg, exitc);
    dtw_stitch<<<dim3(1), dim3(B), 0, stream>>>(seg, exitc, out);
}

// Round 10
// 585.920 us; speedup vs baseline: 1.4575x; 1.1391x over previous
//
#include <hip/hip_runtime.h>

#define TT   1024
#define NW   36          // 32-col windows; slope-2 skew offset up to 126 cols
#define FINF 1e30f
#define SIGN2 0x8000000080000000ULL

template<bool A> struct BoolC { static constexpr bool value = A; };

// dirs layout (bit format as rounds 5-9, skew offset now o = 2L):
//   uint2 {ne2_mask, diag_mask} at ((b*16+bi)*NW + T)*64 + rr
//   window T of the row computed by skew-lane L: bit k = col 32T - 2L + k,
//   L = (bi&3)*16 + (rr>>2). ne2: dir != left. diag: dir == diag (first-min).

// ---------------- K1: forward DP, slope-2 skew, 2 batches per block ---------
// 8 waves = 2 batches (2 waves/SIMD TLP, r9-proven). Wave w owns rows
// 256w..+255 of its batch; lane L owns rows 4L..4L+3. At step t lane L does
// cols 2(t-L), 2(t-L)+1 for its 4 rows = 8 cells per bpermute-wait (the
// exchange passes BOTH neighbor values mid3/fin3 — 2 bpermutes, 1 wait).
// Mailboxes: packed float2 (cols 2i,2i+1) as u64, sign-bit validity.
// cur starts FINF for ALL lanes; (0,0) via the best>9e29 clamp (ACT peel T<4).
__global__ __launch_bounds__(512) void dtw_forward(
    const float* __restrict__ preds,
    const float* __restrict__ targs,
    uint2* __restrict__ dirs)
{
    __shared__ unsigned long long mbox[2][3][512];

    const int tid  = threadIdx.x;
    const int half = tid >> 8;
    const int w    = (tid >> 6) & 3;
    const int lane = tid & 63;
    const int b    = blockIdx.x * 2 + half;

    for (int k = tid; k < 2 * 3 * 512; k += 512)
        ((unsigned long long*)mbox)[k] = SIGN2;     // -0.0f pair = invalid

    float px[4], py[4];
#pragma unroll
    for (int k = 0; k < 4; ++k) {
        const int row = w * 256 + lane * 4 + k;
        float4 pv = ((const float4*)preds)[(size_t)b * TT + row];
        px[k] = pv.x; py[k] = pv.y;
    }
    __syncthreads();

    const unsigned long long* src = (w > 0) ? mbox[half][w - 1] : nullptr;
    unsigned long long*       dst = (w < 3) ? mbox[half][w]     : nullptr;
    const float* qb = targs + (size_t)b * TT * 4;

    float cur0 = FINF, cur1 = FINF, cur2 = FINF, cur3 = FINF;
    float uprev0 = FINF, shpA = FINF, shpB = FINF;
    unsigned au[4] = {0,0,0,0}, ad[4] = {0,0,0,0};
    unsigned long long bn[4] = {0,0,0,0};

    const int bb = b * 16 + 4 * w + (lane >> 4);
    const int r0 = (lane & 15) * 4;
    const bool is63 = (lane == 63);

    for (int T = 0; T < NW; ++T) {
        auto body = [&](auto actc) {
            constexpr bool ACT = decltype(actc)::value;
#pragma unroll 1
            for (int sub = 0; sub < 4; ++sub) {
                const int s0 = 32 * T + 8 * sub;      // global col base of group
                float qx[8], qy[8];
#pragma unroll
                for (int k2 = 0; k2 < 8; ++k2) {
                    const int c = (s0 + k2 - 2 * lane) & (TT - 1);
                    float2 qv = *(const float2*)(qb + c * 4);
                    qx[k2] = qv.x; qy[k2] = qv.y;
                }
                if (w > 0 && s0 < TT) {
                    const int m0 = s0 >> 1;
                    for (;;) {     // JIT validate 8 boundary cols (sign test)
                        unsigned long long sg = 0;
#pragma unroll
                        for (int k2 = 0; k2 < 4; ++k2) {
                            bn[k2] = __hip_atomic_load(src + m0 + k2, __ATOMIC_RELAXED,
                                                       __HIP_MEMORY_SCOPE_WORKGROUP);
                            sg |= bn[k2];
                        }
                        if (!(sg & SIGN2)) break;
                    }
                }
#pragma unroll
                for (int st = 0; st < 4; ++st) {
                    const int t = 16 * T + 4 * sub + st;
                    const float bA = __uint_as_float((unsigned)(bn[st] & 0xffffffffu));
                    const float bB = __uint_as_float((unsigned)(bn[st] >> 32));
                    const float uA = (lane == 0) ? ((w == 0) ? FINF : bA) : shpA;
                    const float uB = (lane == 0) ? ((w == 0) ? FINF : bB) : shpB;
                    const bool act = !ACT || (lane <= t);

                    // ---- column c0 = 2(t-lane) ----
                    {
                        const int q0 = 2 * st;
                        float d0 = __builtin_amdgcn_sqrtf((px[0]-qx[q0])*(px[0]-qx[q0]) + (py[0]-qy[q0])*(py[0]-qy[q0]));
                        float d1 = __builtin_amdgcn_sqrtf((px[1]-qx[q0])*(px[1]-qx[q0]) + (py[1]-qy[q0])*(py[1]-qy[q0]));
                        float d2 = __builtin_amdgcn_sqrtf((px[2]-qx[q0])*(px[2]-qx[q0]) + (py[2]-qy[q0])*(py[2]-qy[q0]));
                        float d3 = __builtin_amdgcn_sqrtf((px[3]-qx[q0])*(px[3]-qx[q0]) + (py[3]-qy[q0])*(py[3]-qy[q0]));
                        float c0o = cur0, c1o = cur1, c2o = cur2, c3o = cur3;
                        float m2a = fminf(uA, c0o);
                        float ba  = fminf(uprev0, m2a);
                        if constexpr (ACT) ba = (ba > 9e29f) ? 0.0f : ba;   // (0,0) only
                        float v0 = d0 + ba;
                        unsigned bd0 = (uprev0 <= m2a) ? 1u : 0u;
                        unsigned bu0 = ((uA <= c0o) ? 1u : 0u) | bd0;
                        float m2b = fminf(v0, c1o);
                        float v1 = d1 + fminf(c0o, m2b);
                        unsigned bd1 = (c0o <= m2b) ? 1u : 0u;
                        unsigned bu1 = ((v0 <= c1o) ? 1u : 0u) | bd1;
                        float m2c = fminf(v1, c2o);
                        float v2 = d2 + fminf(c1o, m2c);
                        unsigned bd2 = (c1o <= m2c) ? 1u : 0u;
                        unsigned bu2 = ((v1 <= c2o) ? 1u : 0u) | bd2;
                        float m2d = fminf(v2, c3o);
                        float v3 = d3 + fminf(c2o, m2d);
                        unsigned bd3 = (c2o <= m2d) ? 1u : 0u;
                        unsigned bu3 = ((v2 <= c3o) ? 1u : 0u) | bd3;
                        au[0] = (au[0] << 1) | bu0;  ad[0] = (ad[0] << 1) | bd0;
                        au[1] = (au[1] << 1) | bu1;  ad[1] = (ad[1] << 1) | bd1;
                        au[2] = (au[2] << 1) | bu2;  ad[2] = (ad[2] << 1) | bd2;
                        au[3] = (au[3] << 1) | bu3;  ad[3] = (ad[3] << 1) | bd3;
                        cur0 = act ? v0 : c0o;  cur1 = act ? v1 : c1o;
                        cur2 = act ? v2 : c2o;  cur3 = act ? v3 : c3o;
                    }
                    const float mid3 = cur3;
                    // ---- column c1 = c0 + 1 (diag of row r0 = uA) ----
                    {
                        const int q1 = 2 * st + 1;
                        float d0 = __builtin_amdgcn_sqrtf((px[0]-qx[q1])*(px[0]-qx[q1]) + (py[0]-qy[q1])*(py[0]-qy[q1]));
                        float d1 = __builtin_amdgcn_sqrtf((px[1]-qx[q1])*(px[1]-qx[q1]) + (py[1]-qy[q1])*(py[1]-qy[q1]));
                        float d2 = __builtin_amdgcn_sqrtf((px[2]-qx[q1])*(px[2]-qx[q1]) + (py[2]-qy[q1])*(py[2]-qy[q1]));
                        float d3 = __builtin_amdgcn_sqrtf((px[3]-qx[q1])*(px[3]-qx[q1]) + (py[3]-qy[q1])*(py[3]-qy[q1]));
                        float c0o = cur0, c1o = cur1, c2o = cur2, c3o = cur3;
                        float m2a = fminf(uB, c0o);
                        float ba  = fminf(uA, m2a);
                        if constexpr (ACT) ba = (ba > 9e29f) ? 0.0f : ba;
                        float v0 = d0 + ba;
                        unsigned bd0 = (uA <= m2a) ? 1u : 0u;
                        unsigned bu0 = ((uB <= c0o) ? 1u : 0u) | bd0;
                        float m2b = fminf(v0, c1o);
                        float v1 = d1 + fminf(c0o, m2b);
                        unsigned bd1 = (c0o <= m2b) ? 1u : 0u;
                        unsigned bu1 = ((v0 <= c1o) ? 1u : 0u) | bd1;
                        float m2c = fminf(v1, c2o);
                        float v2 = d2 + fminf(c1o, m2c);
                        unsigned bd2 = (c1o <= m2c) ? 1u : 0u;
                        unsigned bu2 = ((v1 <= c2o) ? 1u : 0u) | bd2;
                        float m2d = fminf(v2, c3o);
                        float v3 = d3 + fminf(c2o, m2d);
                        unsigned bd3 = (c2o <= m2d) ? 1u : 0u;
                        unsigned bu3 = ((v2 <= c3o) ? 1u : 0u) | bd3;
                        au[0] = (au[0] << 1) | bu0;  ad[0] = (ad[0] << 1) | bd0;
                        au[1] = (au[1] << 1) | bu1;  ad[1] = (ad[1] << 1) | bd1;
                        au[2] = (au[2] << 1) | bu2;  ad[2] = (ad[2] << 1) | bd2;
                        au[3] = (au[3] << 1) | bu3;  ad[3] = (ad[3] << 1) | bd3;
                        cur0 = act ? v0 : c0o;  cur1 = act ? v1 : c1o;
                        cur2 = act ? v2 : c2o;  cur3 = act ? v3 : c3o;
                    }
                    const float fin3 = cur3;
                    uprev0 = uB;
                    if (is63 && w < 3 && (unsigned)(t - 63) < 512u) {
                        unsigned long long pv =
                            ((unsigned long long)__float_as_uint(fin3) << 32) |
                            (unsigned long long)__float_as_uint(mid3);
                        __hip_atomic_store(dst + (t - 63), pv, __ATOMIC_RELAXED,
                                           __HIP_MEMORY_SCOPE_WORKGROUP);
                    }
                    shpA = __shfl_up(mid3, 1);
                    shpB = __shfl_up(fin3, 1);
                }
            }
        };
        if (T < 4) body(BoolC<true>{}); else body(BoolC<false>{});
#pragma unroll
        for (int k = 0; k < 4; ++k) {
            dirs[(size_t)(bb * NW + T) * 64 + r0 + k] =
                make_uint2(__builtin_bitreverse32(au[k]), __builtin_bitreverse32(ad[k]));
            au[k] = 0u; ad[k] = 0u;
        }
    }
}

// ---------------- K2: exit-only per-band walk (no loss) ----------------
__global__ __launch_bounds__(1024) void dtw_exits(
    const uint2* __restrict__ dirs,
    unsigned short* __restrict__ exitc)
{
    __shared__ uint2 raw[NW * 64];
    __shared__ unsigned nebit[64][32];
    __shared__ unsigned dgbit[64][32];

    const int tid = threadIdx.x;
    const int b = blockIdx.x >> 4, bi = blockIdx.x & 15;

    for (int i = tid; i < NW * 64; i += 1024)
        raw[i] = dirs[(size_t)(b * 16 + bi) * (NW * 64) + i];
    __syncthreads();
    for (int i = tid; i < 64 * 32; i += 1024) {
        const int rr = i >> 5, u = i & 31;
        const int o  = (((bi & 3) << 4) + (rr >> 2)) << 1;   // slope-2: o = 2L
        const int T0 = u + (o >> 5), sh = o & 31;
        uint2 A  = raw[T0 * 64 + rr];
        uint2 Bv = raw[(T0 + 1) * 64 + rr];
        nebit[rr][u] = sh ? ((A.x >> sh) | (Bv.x << (32 - sh))) : A.x;
        dgbit[rr][u] = sh ? ((A.y >> sh) | (Bv.y << (32 - sh))) : A.y;
    }
    __syncthreads();

    int j = tid;
    for (int rr = 63; rr >= 0; --rr) {
        if (bi == 0 && rr == 0) { j = 0; break; }
        int u = j >> 5, m = j & 31;
        unsigned wv = nebit[rr][u] << (31 - m);
        while (wv == 0u) { --u; wv = nebit[rr][u]; m = 31; }
        const int j2 = (u << 5) + m - __builtin_clz(wv);
        const int diag = (int)((dgbit[rr][j2 >> 5] >> (j2 & 31)) & 1u);
        j = j2 - diag;
    }
    exitc[((size_t)(b * 16 + bi) << 10) + tid] = (unsigned short)j;
}

// ---------------- K3: stitch -> per-band entry columns ----------------
__global__ void dtw_entries(const unsigned short* __restrict__ exitc,
                            unsigned short* __restrict__ ent)
{
    const int b = threadIdx.x;
    int j = TT - 1;
    for (int bi = 15; bi >= 0; --bi) {
        ent[b * 16 + bi] = (unsigned short)j;
        j = exitc[((size_t)(b * 16 + bi) << 10) + j];
    }
}

// ---------------- K4: loss replay on the 16 true segments per batch --------
__global__ __launch_bounds__(64) void dtw_loss(
    const float* __restrict__ preds,
    const float* __restrict__ targs,
    const float* __restrict__ subcoef,
    const uint2* __restrict__ dirs,
    const unsigned short* __restrict__ ent,
    float* __restrict__ out)
{
    __shared__ uint2 raw[NW * 64];
    __shared__ unsigned nebit[64][32];
    __shared__ unsigned dgbit[64][32];
    __shared__ float2 qsh[TT];
    __shared__ float2 psh[64];
    __shared__ unsigned recs[160];

    const int lane = threadIdx.x;
    const int b = blockIdx.x >> 4, bi = blockIdx.x & 15;

    for (int i = lane; i < NW * 64; i += 64)
        raw[i] = dirs[(size_t)(b * 16 + bi) * (NW * 64) + i];
    for (int k = lane; k < TT; k += 64) {
        float4 t4 = ((const float4*)targs)[(size_t)b * TT + k];
        qsh[k] = make_float2(t4.x, t4.y);
    }
    {
        float4 p4 = ((const float4*)preds)[(size_t)b * TT + bi * 64 + lane];
        psh[lane] = make_float2(p4.x, p4.y);
    }
    __syncthreads();
    for (int i = lane; i < 64 * 32; i += 64) {
        const int rr = i >> 5, u = i & 31;
        const int o  = (((bi & 3) << 4) + (rr >> 2)) << 1;
        const int T0 = u + (o >> 5), sh = o & 31;
        uint2 A  = raw[T0 * 64 + rr];
        uint2 Bv = raw[(T0 + 1) * 64 + rr];
        nebit[rr][u] = sh ? ((A.x >> sh) | (Bv.x << (32 - sh))) : A.x;
        dgbit[rr][u] = sh ? ((A.y >> sh) | (Bv.y << (32 - sh))) : A.y;
    }
    __syncthreads();

    // wave-redundant replay; lane 0 records <=32-col span chunks
    int j = ent[b * 16 + bi];
    int nrec = 0;
    for (int rr = 63; rr >= 0; --rr) {
        int j2;
        if (bi == 0 && rr == 0) j2 = 0;
        else {
            int u = j >> 5, m = j & 31;
            unsigned wv = nebit[rr][u] << (31 - m);
            while (wv == 0u) { --u; wv = nebit[rr][u]; m = 31; }
            j2 = (u << 5) + m - __builtin_clz(wv);
        }
        int c = j;
        for (;;) {
            int cl = (c - 31 > j2) ? (c - 31) : j2;
            if (lane == 0)
                recs[nrec] = ((unsigned)rr << 20) | ((unsigned)cl << 10) | (unsigned)c;
            ++nrec;
            if (cl == j2) break;
            c = cl - 1;
        }
        if (bi == 0 && rr == 0) j = 0;
        else {
            const int diag = (int)((dgbit[rr][j2 >> 5] >> (j2 & 31)) & 1u);
            j = j2 - diag;
        }
    }
    __syncthreads();

    const float sc0 = subcoef[0], sc1 = subcoef[1];
    float acc = 0.0f;
    for (int k = lane; k < nrec; k += 64) {
        unsigned rec = recs[k];
        int rr = (int)(rec >> 20), cl = (int)((rec >> 10) & 1023u), ch = (int)(rec & 1023u);
        float2 p = psh[rr];
        for (int c = cl; c <= ch; ++c) {
            float2 q = qsh[c];
            acc += fabsf(p.x - q.x) * sc0 + fabsf(p.y - q.y) * sc1;
        }
    }
    for (int o = 32; o; o >>= 1) acc += __shfl_down(acc, o);
    if (lane == 0) atomicAdd(out, acc);
}

extern "C" void kernel_launch(void* const* d_in, const int* in_sizes, int n_in,
                              void* d_out, int out_size, void* d_ws, size_t ws_size,
                              hipStream_t stream)
{
    const float* preds   = (const float*)d_in[0];
    const float* targs   = (const float*)d_in[1];
    const float* subcoef = (const float*)d_in[2];
    float* out = (float*)d_out;

    const int B = in_sizes[0] / (TT * 4);

    const size_t dirsBytes = (size_t)B * 16 * NW * 64 * sizeof(uint2);   // ~18.9 MB @ B=64
    const size_t exitBytes = (size_t)B * 16 * 1024 * sizeof(unsigned short);  // 2 MB
    uint2* dirs = (uint2*)d_ws;
    unsigned short* exitc = (unsigned short*)((char*)d_ws + dirsBytes);
    unsigned short* ent   = (unsigned short*)((char*)d_ws + dirsBytes + exitBytes);

    hipMemsetAsync(out, 0, sizeof(float), stream);
    dtw_forward<<<dim3(B / 2), dim3(512), 0, stream>>>(preds, targs, dirs);
    dtw_exits<<<dim3(B * 16), dim3(1024), 0, stream>>>(dirs, exitc);
    dtw_entries<<<dim3(1), dim3(B), 0, stream>>>(exitc, ent);
    dtw_loss<<<dim3(B * 16), dim3(64), 0, stream>>>(preds, targs, subcoef, dirs, ent, out);
}

// Round 11
// 524.146 us; speedup vs baseline: 1.6292x; 1.1179x over previous
//
#include <hip/hip_runtime.h>

#define TT   1024
#define NW   36          // 32-col windows; slope-2 skew offset up to 126 cols
#define FINF 1e30f
#define SIGN2 0x8000000080000000ULL

template<bool A> struct BoolC { static constexpr bool value = A; };

// dirs layout (bit format as rounds 5-10, skew offset o = 2L):
//   uint2 {ne2_mask, diag_mask} at ((b*16+bi)*NW + T)*64 + rr
//   window T of the row computed by skew-lane L: bit k = col 32T - 2L + k,
//   L = (bi&3)*16 + (rr>>2). ne2: dir != left. diag: dir == diag (first-min).

// ---------------- K1: forward DP, one band-wave per block (256 CUs) ---------
// Block = (batch b, band-group w): one wave, rows 256w..256w+255, lane L owns
// rows 4L..4L+3; slope-2 skew (cols 2(t-L), 2(t-L)+1 per step = 8 cells/step).
// Handoff between consecutive w via GLOBAL u64 mailboxes (packed col pair,
// sign-bit validity: costs >= 0 valid; 0xFF/0xAA poison negative). Relaxed
// agent-scope atomics — payload is self-validating, no fence needed; all 256
// blocks co-resident (64 thr each) so spinning cannot deadlock. Mailbox
// groups (8 cols = 4 u64) are prefetched one group ahead -> off-chain.
// cur starts FINF for ALL lanes; (0,0) via the best>9e29 clamp (ACT peel T<4).
__global__ __launch_bounds__(64) void dtw_forward(
    const float* __restrict__ preds,
    const float* __restrict__ targs,
    uint2* __restrict__ dirs,
    unsigned long long* __restrict__ gmbox)   // [B][3][512]
{
    const int lane = threadIdx.x;
    const int b    = blockIdx.x >> 2;
    const int w    = blockIdx.x & 3;

    float px[4], py[4];
#pragma unroll
    for (int k = 0; k < 4; ++k) {
        const int row = w * 256 + lane * 4 + k;
        float4 pv = ((const float4*)preds)[(size_t)b * TT + row];
        px[k] = pv.x; py[k] = pv.y;
    }

    const unsigned long long* src = (w > 0) ? gmbox + ((size_t)b * 3 + (w - 1)) * 512 : nullptr;
    unsigned long long*       dst = (w < 3) ? gmbox + ((size_t)b * 3 + w) * 512 : nullptr;
    const float* qb = targs + (size_t)b * TT * 4;

    float cur0 = FINF, cur1 = FINF, cur2 = FINF, cur3 = FINF;
    float uprev0 = FINF, shpA = FINF, shpB = FINF;
    unsigned au[4] = {0,0,0,0}, ad[4] = {0,0,0,0};
    unsigned long long bnC[4], bnN[4];

    if (w > 0) {   // initial prefetch of group 0 (likely stale; validated below)
#pragma unroll
        for (int k2 = 0; k2 < 4; ++k2)
            bnC[k2] = __hip_atomic_load(src + k2, __ATOMIC_RELAXED, __HIP_MEMORY_SCOPE_AGENT);
    }

    const int bb = b * 16 + 4 * w + (lane >> 4);
    const int r0 = (lane & 15) * 4;
    const bool is63 = (lane == 63);

    for (int T = 0; T < NW; ++T) {
        auto body = [&](auto actc) {
            constexpr bool ACT = decltype(actc)::value;
#pragma unroll 1
            for (int sub = 0; sub < 4; ++sub) {
                const int s0 = 32 * T + 8 * sub;      // global col base of group
                const int g  = s0 >> 3;               // mailbox group index
                float qx[8], qy[8];
#pragma unroll
                for (int k2 = 0; k2 < 8; ++k2) {
                    const int c = (s0 + k2 - 2 * lane) & (TT - 1);
                    float2 qv = *(const float2*)(qb + c * 4);
                    qx[k2] = qv.x; qy[k2] = qv.y;
                }
                if (w > 0 && s0 < TT) {
                    for (;;) {   // validate current group (prefetched)
                        unsigned long long sg = bnC[0] | bnC[1] | bnC[2] | bnC[3];
                        if (!(sg & SIGN2)) break;
#pragma unroll
                        for (int k2 = 0; k2 < 4; ++k2)
                            bnC[k2] = __hip_atomic_load(src + g * 4 + k2, __ATOMIC_RELAXED,
                                                        __HIP_MEMORY_SCOPE_AGENT);
                    }
                    if (s0 + 8 < TT) {   // prefetch next group (off-chain)
#pragma unroll
                        for (int k2 = 0; k2 < 4; ++k2)
                            bnN[k2] = __hip_atomic_load(src + (g + 1) * 4 + k2, __ATOMIC_RELAXED,
                                                        __HIP_MEMORY_SCOPE_AGENT);
                    }
                }
#pragma unroll
                for (int st = 0; st < 4; ++st) {
                    const int t = 16 * T + 4 * sub + st;
                    const float bA = __uint_as_float((unsigned)(bnC[st] & 0xffffffffu));
                    const float bB = __uint_as_float((unsigned)(bnC[st] >> 32));
                    const float uA = (lane == 0) ? ((w == 0) ? FINF : bA) : shpA;
                    const float uB = (lane == 0) ? ((w == 0) ? FINF : bB) : shpB;
                    const bool act = !ACT || (lane <= t);

                    // ---- column c0 = 2(t-lane) ----
                    {
                        const int q0 = 2 * st;
                        float d0 = __builtin_amdgcn_sqrtf((px[0]-qx[q0])*(px[0]-qx[q0]) + (py[0]-qy[q0])*(py[0]-qy[q0]));
                        float d1 = __builtin_amdgcn_sqrtf((px[1]-qx[q0])*(px[1]-qx[q0]) + (py[1]-qy[q0])*(py[1]-qy[q0]));
                        float d2 = __builtin_amdgcn_sqrtf((px[2]-qx[q0])*(px[2]-qx[q0]) + (py[2]-qy[q0])*(py[2]-qy[q0]));
                        float d3 = __builtin_amdgcn_sqrtf((px[3]-qx[q0])*(px[3]-qx[q0]) + (py[3]-qy[q0])*(py[3]-qy[q0]));
                        float c0o = cur0, c1o = cur1, c2o = cur2, c3o = cur3;
                        float m2a = fminf(uA, c0o);
                        float ba  = fminf(uprev0, m2a);
                        if constexpr (ACT) ba = (ba > 9e29f) ? 0.0f : ba;   // (0,0) only
                        float v0 = d0 + ba;
                        unsigned bd0 = (uprev0 <= m2a) ? 1u : 0u;
                        unsigned bu0 = ((uA <= c0o) ? 1u : 0u) | bd0;
                        float m2b = fminf(v0, c1o);
                        float v1 = d1 + fminf(c0o, m2b);
                        unsigned bd1 = (c0o <= m2b) ? 1u : 0u;
                        unsigned bu1 = ((v0 <= c1o) ? 1u : 0u) | bd1;
                        float m2c = fminf(v1, c2o);
                        float v2 = d2 + fminf(c1o, m2c);
                        unsigned bd2 = (c1o <= m2c) ? 1u : 0u;
                        unsigned bu2 = ((v1 <= c2o) ? 1u : 0u) | bd2;
                        float m2d = fminf(v2, c3o);
                        float v3 = d3 + fminf(c2o, m2d);
                        unsigned bd3 = (c2o <= m2d) ? 1u : 0u;
                        unsigned bu3 = ((v2 <= c3o) ? 1u : 0u) | bd3;
                        au[0] = (au[0] << 1) | bu0;  ad[0] = (ad[0] << 1) | bd0;
                        au[1] = (au[1] << 1) | bu1;  ad[1] = (ad[1] << 1) | bd1;
                        au[2] = (au[2] << 1) | bu2;  ad[2] = (ad[2] << 1) | bd2;
                        au[3] = (au[3] << 1) | bu3;  ad[3] = (ad[3] << 1) | bd3;
                        cur0 = act ? v0 : c0o;  cur1 = act ? v1 : c1o;
                        cur2 = act ? v2 : c2o;  cur3 = act ? v3 : c3o;
                    }
                    const float mid3 = cur3;
                    // ---- column c1 = c0 + 1 (diag of row r0 = uA) ----
                    {
                        const int q1 = 2 * st + 1;
                        float d0 = __builtin_amdgcn_sqrtf((px[0]-qx[q1])*(px[0]-qx[q1]) + (py[0]-qy[q1])*(py[0]-qy[q1]));
                        float d1 = __builtin_amdgcn_sqrtf((px[1]-qx[q1])*(px[1]-qx[q1]) + (py[1]-qy[q1])*(py[1]-qy[q1]));
                        float d2 = __builtin_amdgcn_sqrtf((px[2]-qx[q1])*(px[2]-qx[q1]) + (py[2]-qy[q1])*(py[2]-qy[q1]));
                        float d3 = __builtin_amdgcn_sqrtf((px[3]-qx[q1])*(px[3]-qx[q1]) + (py[3]-qy[q1])*(py[3]-qy[q1]));
                        float c0o = cur0, c1o = cur1, c2o = cur2, c3o = cur3;
                        float m2a = fminf(uB, c0o);
                        float ba  = fminf(uA, m2a);
                        if constexpr (ACT) ba = (ba > 9e29f) ? 0.0f : ba;
                        float v0 = d0 + ba;
                        unsigned bd0 = (uA <= m2a) ? 1u : 0u;
                        unsigned bu0 = ((uB <= c0o) ? 1u : 0u) | bd0;
                        float m2b = fminf(v0, c1o);
                        float v1 = d1 + fminf(c0o, m2b);
                        unsigned bd1 = (c0o <= m2b) ? 1u : 0u;
                        unsigned bu1 = ((v0 <= c1o) ? 1u : 0u) | bd1;
                        float m2c = fminf(v1, c2o);
                        float v2 = d2 + fminf(c1o, m2c);
                        unsigned bd2 = (c1o <= m2c) ? 1u : 0u;
                        unsigned bu2 = ((v1 <= c2o) ? 1u : 0u) | bd2;
                        float m2d = fminf(v2, c3o);
                        float v3 = d3 + fminf(c2o, m2d);
                        unsigned bd3 = (c2o <= m2d) ? 1u : 0u;
                        unsigned bu3 = ((v2 <= c3o) ? 1u : 0u) | bd3;
                        au[0] = (au[0] << 1) | bu0;  ad[0] = (ad[0] << 1) | bd0;
                        au[1] = (au[1] << 1) | bu1;  ad[1] = (ad[1] << 1) | bd1;
                        au[2] = (au[2] << 1) | bu2;  ad[2] = (ad[2] << 1) | bd2;
                        au[3] = (au[3] << 1) | bu3;  ad[3] = (ad[3] << 1) | bd3;
                        cur0 = act ? v0 : c0o;  cur1 = act ? v1 : c1o;
                        cur2 = act ? v2 : c2o;  cur3 = act ? v3 : c3o;
                    }
                    const float fin3 = cur3;
                    uprev0 = uB;
                    if (is63 && w < 3 && (unsigned)(t - 63) < 512u) {
                        unsigned long long pv =
                            ((unsigned long long)__float_as_uint(fin3) << 32) |
                            (unsigned long long)__float_as_uint(mid3);
                        __hip_atomic_store(dst + (t - 63), pv, __ATOMIC_RELAXED,
                                           __HIP_MEMORY_SCOPE_AGENT);
                    }
                    shpA = __shfl_up(mid3, 1);
                    shpB = __shfl_up(fin3, 1);
                }
                if (w > 0 && s0 + 8 < TT) {
#pragma unroll
                    for (int k2 = 0; k2 < 4; ++k2) bnC[k2] = bnN[k2];
                }
            }
        };
        if (T < 4) body(BoolC<true>{}); else body(BoolC<false>{});
#pragma unroll
        for (int k = 0; k < 4; ++k) {
            dirs[(size_t)(bb * NW + T) * 64 + r0 + k] =
                make_uint2(__builtin_bitreverse32(au[k]), __builtin_bitreverse32(ad[k]));
            au[k] = 0u; ad[k] = 0u;
        }
    }
}

// ---------------- K2: exit-only per-band walk (no loss) ----------------
__global__ __launch_bounds__(1024) void dtw_exits(
    const uint2* __restrict__ dirs,
    unsigned short* __restrict__ exitc)
{
    __shared__ uint2 raw[NW * 64];
    __shared__ unsigned nebit[64][32];
    __shared__ unsigned dgbit[64][32];

    const int tid = threadIdx.x;
    const int b = blockIdx.x >> 4, bi = blockIdx.x & 15;

    for (int i = tid; i < NW * 64; i += 1024)
        raw[i] = dirs[(size_t)(b * 16 + bi) * (NW * 64) + i];
    __syncthreads();
    for (int i = tid; i < 64 * 32; i += 1024) {
        const int rr = i >> 5, u = i & 31;
        const int o  = (((bi & 3) << 4) + (rr >> 2)) << 1;   // slope-2: o = 2L
        const int T0 = u + (o >> 5), sh = o & 31;
        uint2 A  = raw[T0 * 64 + rr];
        uint2 Bv = raw[(T0 + 1) * 64 + rr];
        nebit[rr][u] = sh ? ((A.x >> sh) | (Bv.x << (32 - sh))) : A.x;
        dgbit[rr][u] = sh ? ((A.y >> sh) | (Bv.y << (32 - sh))) : A.y;
    }
    __syncthreads();

    int j = tid;
    for (int rr = 63; rr >= 0; --rr) {
        if (bi == 0 && rr == 0) { j = 0; break; }
        int u = j >> 5, m = j & 31;
        unsigned wv = nebit[rr][u] << (31 - m);
        while (wv == 0u) { --u; wv = nebit[rr][u]; m = 31; }
        const int j2 = (u << 5) + m - __builtin_clz(wv);
        const int diag = (int)((dgbit[rr][j2 >> 5] >> (j2 & 31)) & 1u);
        j = j2 - diag;
    }
    exitc[((size_t)(b * 16 + bi) << 10) + tid] = (unsigned short)j;
}

// ---------------- K3: stitch -> per-band entry columns ----------------
__global__ void dtw_entries(const unsigned short* __restrict__ exitc,
                            unsigned short* __restrict__ ent)
{
    const int b = threadIdx.x;
    int j = TT - 1;
    for (int bi = 15; bi >= 0; --bi) {
        ent[b * 16 + bi] = (unsigned short)j;
        j = exitc[((size_t)(b * 16 + bi) << 10) + j];
    }
}

// ---------------- K4: loss replay on the 16 true segments per batch --------
__global__ __launch_bounds__(64) void dtw_loss(
    const float* __restrict__ preds,
    const float* __restrict__ targs,
    const float* __restrict__ subcoef,
    const uint2* __restrict__ dirs,
    const unsigned short* __restrict__ ent,
    float* __restrict__ out)
{
    __shared__ uint2 raw[NW * 64];
    __shared__ unsigned nebit[64][32];
    __shared__ unsigned dgbit[64][32];
    __shared__ float2 qsh[TT];
    __shared__ float2 psh[64];
    __shared__ unsigned recs[160];

    const int lane = threadIdx.x;
    const int b = blockIdx.x >> 4, bi = blockIdx.x & 15;

    for (int i = lane; i < NW * 64; i += 64)
        raw[i] = dirs[(size_t)(b * 16 + bi) * (NW * 64) + i];
    for (int k = lane; k < TT; k += 64) {
        float4 t4 = ((const float4*)targs)[(size_t)b * TT + k];
        qsh[k] = make_float2(t4.x, t4.y);
    }
    {
        float4 p4 = ((const float4*)preds)[(size_t)b * TT + bi * 64 + lane];
        psh[lane] = make_float2(p4.x, p4.y);
    }
    __syncthreads();
    for (int i = lane; i < 64 * 32; i += 64) {
        const int rr = i >> 5, u = i & 31;
        const int o  = (((bi & 3) << 4) + (rr >> 2)) << 1;
        const int T0 = u + (o >> 5), sh = o & 31;
        uint2 A  = raw[T0 * 64 + rr];
        uint2 Bv = raw[(T0 + 1) * 64 + rr];
        nebit[rr][u] = sh ? ((A.x >> sh) | (Bv.x << (32 - sh))) : A.x;
        dgbit[rr][u] = sh ? ((A.y >> sh) | (Bv.y << (32 - sh))) : A.y;
    }
    __syncthreads();

    // wave-redundant replay; lane 0 records <=32-col span chunks
    int j = ent[b * 16 + bi];
    int nrec = 0;
    for (int rr = 63; rr >= 0; --rr) {
        int j2;
        if (bi == 0 && rr == 0) j2 = 0;
        else {
            int u = j >> 5, m = j & 31;
            unsigned wv = nebit[rr][u] << (31 - m);
            while (wv == 0u) { --u; wv = nebit[rr][u]; m = 31; }
            j2 = (u << 5) + m - __builtin_clz(wv);
        }
        int c = j;
        for (;;) {
            int cl = (c - 31 > j2) ? (c - 31) : j2;
            if (lane == 0)
                recs[nrec] = ((unsigned)rr << 20) | ((unsigned)cl << 10) | (unsigned)c;
            ++nrec;
            if (cl == j2) break;
            c = cl - 1;
        }
        if (bi == 0 && rr == 0) j = 0;
        else {
            const int diag = (int)((dgbit[rr][j2 >> 5] >> (j2 & 31)) & 1u);
            j = j2 - diag;
        }
    }
    __syncthreads();

    const float sc0 = subcoef[0], sc1 = subcoef[1];
    float acc = 0.0f;
    for (int k = lane; k < nrec; k += 64) {
        unsigned rec = recs[k];
        int rr = (int)(rec >> 20), cl = (int)((rec >> 10) & 1023u), ch = (int)(rec & 1023u);
        float2 p = psh[rr];
        for (int c = cl; c <= ch; ++c) {
            float2 q = qsh[c];
            acc += fabsf(p.x - q.x) * sc0 + fabsf(p.y - q.y) * sc1;
        }
    }
    for (int o = 32; o; o >>= 1) acc += __shfl_down(acc, o);
    if (lane == 0) atomicAdd(out, acc);
}

extern "C" void kernel_launch(void* const* d_in, const int* in_sizes, int n_in,
                              void* d_out, int out_size, void* d_ws, size_t ws_size,
                              hipStream_t stream)
{
    const float* preds   = (const float*)d_in[0];
    const float* targs   = (const float*)d_in[1];
    const float* subcoef = (const float*)d_in[2];
    float* out = (float*)d_out;

    const int B = in_sizes[0] / (TT * 4);

    const size_t dirsBytes = (size_t)B * 16 * NW * 64 * sizeof(uint2);        // ~18.9 MB
    const size_t exitBytes = (size_t)B * 16 * 1024 * sizeof(unsigned short);  // 2 MB
    const size_t entBytes  = (size_t)B * 16 * sizeof(unsigned short);
    uint2* dirs = (uint2*)d_ws;
    unsigned short* exitc = (unsigned short*)((char*)d_ws + dirsBytes);
    unsigned short* ent   = (unsigned short*)((char*)d_ws + dirsBytes + exitBytes);
    unsigned long long* gmbox =
        (unsigned long long*)((char*)d_ws + dirsBytes + exitBytes + ((entBytes + 255) & ~255ULL));

    hipMemsetAsync(out, 0, sizeof(float), stream);
    hipMemsetAsync(gmbox, 0xFF, (size_t)B * 3 * 512 * 8, stream);   // sign bit set = invalid
    dtw_forward<<<dim3(B * 4), dim3(64), 0, stream>>>(preds, targs, dirs, gmbox);
    dtw_exits<<<dim3(B * 16), dim3(1024), 0, stream>>>(dirs, exitc);
    dtw_entries<<<dim3(1), dim3(B), 0, stream>>>(exitc, ent);
    dtw_loss<<<dim3(B * 16), dim3(64), 0, stream>>>(preds, targs, subcoef, dirs, ent, out);
}

// Round 12
// 418.601 us; speedup vs baseline: 2.0400x; 1.2521x over previous
//
#include <hip/hip_runtime.h>

#define TT   1024
#define NW   34          // 32-step windows; slope-1 skew offset up to 63
#define FINF 1e30f

template<bool A> struct BoolC { static constexpr bool value = A; };

// dirs layout (bit format as earlier rounds, keyed by 64-row band):
//   uint2 {ne2_mask, diag_mask} at ((b*16+bi)*NW + T)*64 + rr
//   bit k of window T = col 32T - o + k, o = skew lane of row rr:
//   o = (bi&1)*32 + (rr>>1)  [8 waves x 128 rows, 2 rows/lane, slope-1]
// ne2: dir != left. diag: dir == diag (first-min argmin).

// ---------------- K1: forward DP, 1 batch/block, 8 waves, LDS-only ----------
// Wave w owns rows 128w..128w+127; lane L owns rows 128w+2L, +2L+1. Slope-1
// skew: at step s lane L computes col s-L for its 2 rows (chain = shfl + 2
// cells). ALL handoff via LDS mailboxes (sign-bit validity: costs >= 0 valid,
// -1.0f init negative) — no global atomics in the loop (r11's agent-scope
// stores thrashed L1: FETCH_SIZE 4x, 91% stall). q staged in LDS (lgkm-only
// loop). Grid=B -> 64 CUs, 2 waves/SIMD TLP (r9-proven level).
// cur starts FINF for ALL lanes; (0,0) via the best>9e29 clamp (ACT peel T<2).
__global__ __launch_bounds__(512) void dtw_forward(
    const float* __restrict__ preds,
    const float* __restrict__ targs,
    uint2* __restrict__ dirs)
{
    __shared__ float2 qsh[TT];
    __shared__ float mbox[7][TT];

    const int tid  = threadIdx.x;
    const int w    = tid >> 6;
    const int lane = tid & 63;
    const int b    = blockIdx.x;

    for (int k = tid; k < TT; k += 512) {
        float4 t4 = ((const float4*)targs)[(size_t)b * TT + k];
        qsh[k] = make_float2(t4.x, t4.y);
    }
    for (int k = tid; k < 7 * TT; k += 512) ((float*)mbox)[k] = -1.0f;

    float pxA, pyA, pxB, pyB;
    {
        const int rowA = w * 128 + 2 * lane;
        float4 pv = ((const float4*)preds)[(size_t)b * TT + rowA];
        pxA = pv.x; pyA = pv.y;
        float4 pw = ((const float4*)preds)[(size_t)b * TT + rowA + 1];
        pxB = pw.x; pyB = pw.y;
    }
    __syncthreads();

    const float* src = (w > 0) ? mbox[w - 1] : nullptr;
    float*       dst = (w < 7) ? mbox[w]     : nullptr;

    float curA = FINF, curB = FINF, uprev = FINF, shp = FINF;
    unsigned auA = 0, adA = 0, auB = 0, adB = 0;
    float bnd[8];
#pragma unroll
    for (int k = 0; k < 8; ++k) bnd[k] = FINF;

    const int bi  = 2 * w + (lane >> 5);     // 64-row band index (within batch)
    const int rr0 = 2 * (lane & 31);         // row within band
    const bool is63 = (lane == 63);

    for (int T = 0; T < NW; ++T) {
        auto body = [&](auto actc) {
            constexpr bool ACT = decltype(actc)::value;
#pragma unroll 1
            for (int sub = 0; sub < 4; ++sub) {
                const int s0 = 32 * T + 8 * sub;
                // q for this 8-group: LDS -> regs (conflict-free, off-chain)
                float qx[8], qy[8];
#pragma unroll
                for (int k2 = 0; k2 < 8; ++k2) {
                    float2 qv = qsh[(s0 + k2 - lane) & (TT - 1)];
                    qx[k2] = qv.x; qy[k2] = qv.y;
                }
                if (w > 0 && s0 < TT) {
                    for (;;) {   // JIT validate boundary cols (sign-bit test)
                        unsigned sg = 0u;
#pragma unroll
                        for (int k2 = 0; k2 < 8; ++k2) {
                            bnd[k2] = __hip_atomic_load(src + s0 + k2, __ATOMIC_RELAXED,
                                                        __HIP_MEMORY_SCOPE_WORKGROUP);
                            sg |= __float_as_uint(bnd[k2]);
                        }
                        if (!(sg & 0x80000000u)) break;
                        __builtin_amdgcn_s_sleep(1);   // don't starve SIMD partner
                    }
                }
#pragma unroll
                for (int k2 = 0; k2 < 8; ++k2) {
                    const int s = s0 + k2;
                    const float dA = __builtin_amdgcn_sqrtf(
                        (pxA - qx[k2]) * (pxA - qx[k2]) + (pyA - qy[k2]) * (pyA - qy[k2]));
                    const float dB = __builtin_amdgcn_sqrtf(
                        (pxB - qx[k2]) * (pxB - qx[k2]) + (pyB - qy[k2]) * (pyB - qy[k2]));

                    const float u = (lane == 0) ? ((w == 0) ? FINF : bnd[k2]) : shp;
                    const float cAo = curA, cBo = curB;

                    // row A: cd=uprev, cu=u, cl=cAo (clamp fires only at (0,0))
                    float m2a = fminf(u, cAo);
                    float ba  = fminf(uprev, m2a);
                    if constexpr (ACT) ba = (ba > 9e29f) ? 0.0f : ba;
                    float vA = dA + ba;
                    unsigned bdA = (uprev <= m2a) ? 1u : 0u;
                    unsigned buA = ((u <= cAo) ? 1u : 0u) | bdA;
                    // row B: cd=cAo, cu=vA, cl=cBo
                    float m2b = fminf(vA, cBo);
                    float vB = dB + fminf(cAo, m2b);
                    unsigned bdB = (cAo <= m2b) ? 1u : 0u;
                    unsigned buB = ((vA <= cBo) ? 1u : 0u) | bdB;

                    auA = (auA << 1) | buA;  adA = (adA << 1) | bdA;
                    auB = (auB << 1) | buB;  adB = (adB << 1) | bdB;

                    if constexpr (ACT) {
                        const bool act = (lane <= s);
                        curA = act ? vA : cAo;
                        curB = act ? vB : cBo;
                    } else {
                        curA = vA; curB = vB;
                    }
                    uprev = u;

                    if (is63 && w < 7 && (unsigned)(s - 63) < 1024u)
                        __hip_atomic_store(dst + (s - 63), curB, __ATOMIC_RELAXED,
                                           __HIP_MEMORY_SCOPE_WORKGROUP);

                    shp = __shfl_up(curB, 1);   // for next step (col s+1-L)
                }
            }
        };
        if (T < 2) body(BoolC<true>{}); else body(BoolC<false>{});
        dirs[(size_t)((b * 16 + bi) * NW + T) * 64 + rr0] =
            make_uint2(__builtin_bitreverse32(auA), __builtin_bitreverse32(adA));
        dirs[(size_t)((b * 16 + bi) * NW + T) * 64 + rr0 + 1] =
            make_uint2(__builtin_bitreverse32(auB), __builtin_bitreverse32(adB));
        auA = adA = auB = adB = 0u;
    }
}

// ---------------- K2: exit-only per-band walk (no loss) ----------------
__global__ __launch_bounds__(1024) void dtw_exits(
    const uint2* __restrict__ dirs,
    unsigned short* __restrict__ exitc)
{
    __shared__ uint2 raw[NW * 64];
    __shared__ unsigned nebit[64][32];
    __shared__ unsigned dgbit[64][32];

    const int tid = threadIdx.x;
    const int b = blockIdx.x >> 4, bi = blockIdx.x & 15;

    for (int i = tid; i < NW * 64; i += 1024)
        raw[i] = dirs[(size_t)(b * 16 + bi) * (NW * 64) + i];
    __syncthreads();
    for (int i = tid; i < 64 * 32; i += 1024) {
        const int rr = i >> 5, u = i & 31;
        const int o  = ((bi & 1) << 5) + (rr >> 1);   // slope-1, 2 rows/lane
        const int T0 = u + (o >> 5), sh = o & 31;
        uint2 A  = raw[T0 * 64 + rr];
        uint2 Bv = raw[(T0 + 1) * 64 + rr];
        nebit[rr][u] = sh ? ((A.x >> sh) | (Bv.x << (32 - sh))) : A.x;
        dgbit[rr][u] = sh ? ((A.y >> sh) | (Bv.y << (32 - sh))) : A.y;
    }
    __syncthreads();

    int j = tid;
    for (int rr = 63; rr >= 0; --rr) {
        if (bi == 0 && rr == 0) { j = 0; break; }
        int u = j >> 5, m = j & 31;
        unsigned wv = nebit[rr][u] << (31 - m);
        while (wv == 0u) { --u; wv = nebit[rr][u]; m = 31; }
        const int j2 = (u << 5) + m - __builtin_clz(wv);
        const int diag = (int)((dgbit[rr][j2 >> 5] >> (j2 & 31)) & 1u);
        j = j2 - diag;
    }
    exitc[((size_t)(b * 16 + bi) << 10) + tid] = (unsigned short)j;
}

// ---------------- K3: stitch -> per-band entry columns ----------------
__global__ void dtw_entries(const unsigned short* __restrict__ exitc,
                            unsigned short* __restrict__ ent)
{
    const int b = threadIdx.x;
    int j = TT - 1;
    for (int bi = 15; bi >= 0; --bi) {
        ent[b * 16 + bi] = (unsigned short)j;
        j = exitc[((size_t)(b * 16 + bi) << 10) + j];
    }
}

// ---------------- K4: loss replay on the 16 true segments per batch --------
__global__ __launch_bounds__(64) void dtw_loss(
    const float* __restrict__ preds,
    const float* __restrict__ targs,
    const float* __restrict__ subcoef,
    const uint2* __restrict__ dirs,
    const unsigned short* __restrict__ ent,
    float* __restrict__ out)
{
    __shared__ uint2 raw[NW * 64];
    __shared__ unsigned nebit[64][32];
    __shared__ unsigned dgbit[64][32];
    __shared__ float2 qsh[TT];
    __shared__ float2 psh[64];
    __shared__ unsigned recs[160];

    const int lane = threadIdx.x;
    const int b = blockIdx.x >> 4, bi = blockIdx.x & 15;

    for (int i = lane; i < NW * 64; i += 64)
        raw[i] = dirs[(size_t)(b * 16 + bi) * (NW * 64) + i];
    for (int k = lane; k < TT; k += 64) {
        float4 t4 = ((const float4*)targs)[(size_t)b * TT + k];
        qsh[k] = make_float2(t4.x, t4.y);
    }
    {
        float4 p4 = ((const float4*)preds)[(size_t)b * TT + bi * 64 + lane];
        psh[lane] = make_float2(p4.x, p4.y);
    }
    __syncthreads();
    for (int i = lane; i < 64 * 32; i += 64) {
        const int rr = i >> 5, u = i & 31;
        const int o  = ((bi & 1) << 5) + (rr >> 1);   // slope-1, 2 rows/lane
        const int T0 = u + (o >> 5), sh = o & 31;
        uint2 A  = raw[T0 * 64 + rr];
        uint2 Bv = raw[(T0 + 1) * 64 + rr];
        nebit[rr][u] = sh ? ((A.x >> sh) | (Bv.x << (32 - sh))) : A.x;
        dgbit[rr][u] = sh ? ((A.y >> sh) | (Bv.y << (32 - sh))) : A.y;
    }
    __syncthreads();

    // wave-redundant replay; lane 0 records <=32-col span chunks
    int j = ent[b * 16 + bi];
    int nrec = 0;
    for (int rr = 63; rr >= 0; --rr) {
        int j2;
        if (bi == 0 && rr == 0) j2 = 0;
        else {
            int u = j >> 5, m = j & 31;
            unsigned wv = nebit[rr][u] << (31 - m);
            while (wv == 0u) { --u; wv = nebit[rr][u]; m = 31; }
            j2 = (u << 5) + m - __builtin_clz(wv);
        }
        int c = j;
        for (;;) {
            int cl = (c - 31 > j2) ? (c - 31) : j2;
            if (lane == 0)
                recs[nrec] = ((unsigned)rr << 20) | ((unsigned)cl << 10) | (unsigned)c;
            ++nrec;
            if (cl == j2) break;
            c = cl - 1;
        }
        if (bi == 0 && rr == 0) j = 0;
        else {
            const int diag = (int)((dgbit[rr][j2 >> 5] >> (j2 & 31)) & 1u);
            j = j2 - diag;
        }
    }
    __syncthreads();

    const float sc0 = subcoef[0], sc1 = subcoef[1];
    float acc = 0.0f;
    for (int k = lane; k < nrec; k += 64) {
        unsigned rec = recs[k];
        int rr = (int)(rec >> 20), cl = (int)((rec >> 10) & 1023u), ch = (int)(rec & 1023u);
        float2 p = psh[rr];
        for (int c = cl; c <= ch; ++c) {
            float2 q = qsh[c];
            acc += fabsf(p.x - q.x) * sc0 + fabsf(p.y - q.y) * sc1;
        }
    }
    for (int o = 32; o; o >>= 1) acc += __shfl_down(acc, o);
    if (lane == 0) atomicAdd(out, acc);
}

extern "C" void kernel_launch(void* const* d_in, const int* in_sizes, int n_in,
                              void* d_out, int out_size, void* d_ws, size_t ws_size,
                              hipStream_t stream)
{
    const float* preds   = (const float*)d_in[0];
    const float* targs   = (const float*)d_in[1];
    const float* subcoef = (const float*)d_in[2];
    float* out = (float*)d_out;

    const int B = in_sizes[0] / (TT * 4);

    const size_t dirsBytes = (size_t)B * 16 * NW * 64 * sizeof(uint2);        // ~17.8 MB
    const size_t exitBytes = (size_t)B * 16 * 1024 * sizeof(unsigned short);  // 2 MB
    uint2* dirs = (uint2*)d_ws;
    unsigned short* exitc = (unsigned short*)((char*)d_ws + dirsBytes);
    unsigned short* ent   = (unsigned short*)((char*)d_ws + dirsBytes + exitBytes);

    hipMemsetAsync(out, 0, sizeof(float), stream);
    dtw_forward<<<dim3(B), dim3(512), 0, stream>>>(preds, targs, dirs);
    dtw_exits<<<dim3(B * 16), dim3(1024), 0, stream>>>(dirs, exitc);
    dtw_entries<<<dim3(1), dim3(B), 0, stream>>>(exitc, ent);
    dtw_loss<<<dim3(B * 16), dim3(64), 0, stream>>>(preds, targs, subcoef, dirs, ent, out);
}